// Round 5
// baseline (139.174 us; speedup 1.0000x reference)
//
#include <hip/hip_runtime.h>
#include <hip/hip_fp16.h>

// Trilinear 3D-LUT interpolation (image-adaptive-3DLUT forward).
// lut: [3, 33, 33, 33] fp32, x: [4, 3, 1024, 1024] fp32 in [0,1], out same as x.
//
// R4b: cell-table design (R4) with the cvt_pkrtz type fixed (bit-cast union).
// Pre-pack a CELL TABLE: for each of the 32^3 query cells, all 8 corners x 3
// channels as 24 fp16 in one 64B-aligned entry (48 B used, 2 MB total ->
// L2-resident, ~128x reuse per cell). Main kernel: per pixel, ONE line of
// gathers (3x global_load_dwordx4), weights computed once for all 3 channels,
// 12x v_dot2_f32_f16 accumulate. x read ONCE -> HBM ~100 MB ideal; no LDS.

#define LUT_D  33
#define LUT_DD (LUT_D * LUT_D)            // 1089
#define LUT_N  (LUT_D * LUT_D * LUT_D)    // 35937
#define HW4    (1024 * 1024 / 4)          // 262144 float4 groups per plane
#define NG     (4 * HW4)                  // 1048576 float4 groups total
#define CELLS  (32 * 32 * 32)             // 32768

typedef _Float16 half2v  __attribute__((ext_vector_type(2)));
typedef __fp16   fp16x2  __attribute__((ext_vector_type(2)));
typedef float    vfloat4 __attribute__((ext_vector_type(4)));

// Cell table: 16 u32 (64 B) per cell, words 0..11 used:
//   word[c*4 + ob*2 + og] = half2( v[c][ib+ob][ig+og][ir+0], v[...][ir+1] )
__device__ __align__(64) unsigned int g_cells[CELLS * 16];  // 2 MiB device-global

union U32H2 { unsigned int u; half2v h; fp16x2 f; __half2 hh; };

__device__ __forceinline__ half2v as_h2(unsigned int u) {
    U32H2 cv; cv.u = u; return cv.h;
}

__device__ __forceinline__ half2v pk_h2(float a, float b) {
    U32H2 cv; cv.f = __builtin_amdgcn_cvt_pkrtz(a, b);  // v_cvt_pkrtz_f16_f32
    return cv.h;
}

__device__ __forceinline__ float dot_h2(half2v a, half2v b, float acc) {
    return __builtin_amdgcn_fdot2(a, b, acc, false);     // v_dot2_f32_f16
}

// ---- Pass 1: build the cell table (one thread per cell).
__global__ __launch_bounds__(256)
void cell_pack_kernel(const float* __restrict__ lut) {
    const int id = blockIdx.x * 256 + (int)threadIdx.x;   // [0, 32768)
    const int ir = id & 31;
    const int ig = (id >> 5) & 31;
    const int ib = id >> 10;
    const int base = (ib * LUT_D + ig) * LUT_D + ir;

    unsigned int w[12];
#pragma unroll
    for (int c = 0; c < 3; ++c) {
        const float* L = lut + c * LUT_N + base;
#pragma unroll
        for (int ob = 0; ob < 2; ++ob) {
#pragma unroll
            for (int og = 0; og < 2; ++og) {
                const float* p = L + ob * LUT_DD + og * LUT_D;
                U32H2 cv; cv.hh = __floats2half2_rn(p[0], p[1]);  // lo=ir, hi=ir+1
                w[c * 4 + ob * 2 + og] = cv.u;
            }
        }
    }
    uint4* dst = (uint4*)(g_cells + (id << 4));
    dst[0] = make_uint4(w[0], w[1], w[2],  w[3]);   // channel 0
    dst[1] = make_uint4(w[4], w[5], w[6],  w[7]);   // channel 1
    dst[2] = make_uint4(w[8], w[9], w[10], w[11]);  // channel 2
    // words 12..15: pad, never read
}

// ---- Pass 2: main interpolation. One thread = 4 pixels (float4 groups),
// all 3 channels in/out. x read once; gathers are single-line dwordx4 triples.
__global__ __launch_bounds__(256)
void lut3d_cell_kernel(const float* __restrict__ x, float* __restrict__ out) {
    const int g     = blockIdx.x * 256 + (int)threadIdx.x;  // [0, NG)
    const int b_img = g >> 18;            // g / HW4
    const int hw4   = g & (HW4 - 1);
    const int ibase = b_img * 3 * HW4 + hw4;

    const float4* x4 = (const float4*)x;
    float4*       o4 = (float4*)out;

    const float4 r4 = x4[ibase];
    const float4 g4 = x4[ibase + HW4];
    const float4 b4 = x4[ibase + 2 * HW4];

    const float RR[4] = {r4.x, r4.y, r4.z, r4.w};
    const float GG[4] = {g4.x, g4.y, g4.z, g4.w};
    const float BB[4] = {b4.x, b4.y, b4.z, b4.w};
    float o0[4], o1[4], o2[4];

#pragma unroll
    for (int k = 0; k < 4; ++k) {
        const float sr = RR[k] * 32.0f;
        const float sg = GG[k] * 32.0f;
        const float sb = BB[k] * 32.0f;
        // idx = clip(floor(s), 0, 31); d = s - idx   (matches reference)
        const float fr = fminf(fmaxf(floorf(sr), 0.0f), 31.0f);
        const float fg = fminf(fmaxf(floorf(sg), 0.0f), 31.0f);
        const float fb = fminf(fmaxf(floorf(sb), 0.0f), 31.0f);
        const float dr = sr - fr;
        const float dg = sg - fg;
        const float db = sb - fb;

        const int cell = ((int)fb << 10) | ((int)fg << 5) | (int)fr;
        const uint4* cp = (const uint4*)(g_cells + (cell << 4));
        const uint4 q0 = cp[0];   // one 64B line: q1/q2 hit L1 behind q0's fill
        const uint4 q1 = cp[1];
        const uint4 q2 = cp[2];

        const float wr0 = 1.0f - dr;
        const float wg0 = 1.0f - dg;
        const float wb0 = 1.0f - db;
        const float p00 = wb0 * wg0;   // (ob=0, og=0)
        const float p01 = wb0 * dg;    // (ob=0, og=1)
        const float p10 = db  * wg0;   // (ob=1, og=0)
        const float p11 = db  * dg;    // (ob=1, og=1)
        const half2v w0 = pk_h2(p00 * wr0, p00 * dr);
        const half2v w1 = pk_h2(p01 * wr0, p01 * dr);
        const half2v w2 = pk_h2(p10 * wr0, p10 * dr);
        const half2v w3 = pk_h2(p11 * wr0, p11 * dr);

        o0[k] = dot_h2(as_h2(q0.x), w0,
                dot_h2(as_h2(q0.y), w1,
                dot_h2(as_h2(q0.z), w2,
                dot_h2(as_h2(q0.w), w3, 0.0f))));
        o1[k] = dot_h2(as_h2(q1.x), w0,
                dot_h2(as_h2(q1.y), w1,
                dot_h2(as_h2(q1.z), w2,
                dot_h2(as_h2(q1.w), w3, 0.0f))));
        o2[k] = dot_h2(as_h2(q2.x), w0,
                dot_h2(as_h2(q2.y), w1,
                dot_h2(as_h2(q2.z), w2,
                dot_h2(as_h2(q2.w), w3, 0.0f))));
    }

    vfloat4 v0 = {o0[0], o0[1], o0[2], o0[3]};
    vfloat4 v1 = {o1[0], o1[1], o1[2], o1[3]};
    vfloat4 v2 = {o2[0], o2[1], o2[2], o2[3]};
    __builtin_nontemporal_store(v0, (vfloat4*)&o4[ibase]);
    __builtin_nontemporal_store(v1, (vfloat4*)&o4[ibase + HW4]);
    __builtin_nontemporal_store(v2, (vfloat4*)&o4[ibase + 2 * HW4]);
}

extern "C" void kernel_launch(void* const* d_in, const int* in_sizes, int n_in,
                              void* d_out, int out_size, void* d_ws, size_t ws_size,
                              hipStream_t stream) {
    const float* lut = (const float*)d_in[0];  // [3, 33, 33, 33]
    const float* x   = (const float*)d_in[1];  // [4, 3, 1024, 1024]
    float*       out = (float*)d_out;

    cell_pack_kernel<<<CELLS / 256, 256, 0, stream>>>(lut);      // 128 blocks
    lut3d_cell_kernel<<<NG / 256, 256, 0, stream>>>(x, out);     // 4096 blocks
}